// Round 2
// baseline (38782.809 us; speedup 1.0000x reference)
//
#include <hip/hip_runtime.h>

#define Bsz 4096
#define Lsz 128
#define NI  127
#define SD  32
#define AD  8
#define XDm 9
#define LAT 64
#define HID 128
#define BT  16
#define THR 1024

// ---------------- W2 repack: [128][576] -> [j][l][12] (16B-aligned rows of 9+3pad) ----------------
__global__ __launch_bounds__(256) void repack_w2(const float* __restrict__ W2, float* __restrict__ W2p){
  int idx = blockIdx.x*256 + threadIdx.x;
  if (idx >= HID*LAT*12) return;
  int x = idx % 12; int jl = idx / 12; int l = jl % LAT; int j = jl / LAT;
  W2p[idx] = (x < XDm) ? W2[j*(LAT*XDm) + l*XDm + x] : 0.f;
}

// ---------------- Natural cubic spline: Thomas solve per (b,channel) ----------------
// m_ws layout [i][b][c], i=0..127 (m[0]=m[127]=0)
__global__ __launch_bounds__(256) void spline_kernel(const float* __restrict__ t,
                                                     const float* __restrict__ a,
                                                     float* __restrict__ m_ws){
  __shared__ float cp_s[126];
  if (threadIdx.x == 0){
    float c = 0.25f; cp_s[0] = c;
    for (int i=1;i<126;i++){ c = 1.0f/(4.0f - c); cp_s[i] = c; }
  }
  __syncthreads();
  int tid = blockIdx.x*256 + threadIdx.x;   // tid = b*9 + c
  int b = tid/XDm, c = tid%XDm;
  float dp[126];
  const float* tb = t + (size_t)b*Lsz;
  const float* ab = a + (size_t)b*Lsz*AD + (c-1);
  float x0 = (c==0)? tb[0] : ab[0];
  float x1 = (c==0)? tb[1] : ab[AD];
  for (int i=0;i<126;i++){
    float x2 = (c==0)? tb[i+2] : ab[(size_t)(i+2)*AD];
    float rhs = 6.0f*(x2 - 2.0f*x1 + x0);
    dp[i] = (i==0)? rhs*0.25f : (rhs - dp[i-1])*cp_s[i];
    x0 = x1; x1 = x2;
  }
  m_ws[tid] = 0.0f;                               // m[0]
  m_ws[(size_t)127*(Bsz*XDm) + tid] = 0.0f;       // m[127]
  float mn = 0.0f;
  for (int k=125;k>=0;k--){
    mn = dp[k] - cp_s[k]*mn;
    m_ws[(size_t)(k+1)*(Bsz*XDm) + tid] = mn;
  }
}

// ---------------- Persistent RK4 integrator: 1024 threads, 16 batch/block, 4 waves/SIMD ----------------
__global__ __launch_bounds__(THR, 4) void cde_integrate(
    const float* __restrict__ s, const float* __restrict__ a, const float* __restrict__ t,
    const float* __restrict__ encW, const float* __restrict__ encb,
    const float* __restrict__ W1, const float* __restrict__ b1,
    const float* __restrict__ b2, const float* __restrict__ decW, const float* __restrict__ decb,
    const float* __restrict__ W2p, const float* __restrict__ m_ws,
    float* __restrict__ out)
{
  __shared__ float W1t[HID][LAT+4];    // transposed [j][k], pad 68 (rows 16B-aligned)
  __shared__ float hs[BT][HID+4];      // pad 132
  __shared__ float zs[BT][LAT+4];      // pad 68
  __shared__ float dXs[5][BT][XDm];    // dX at u in {0,.25,.5,.75,1}
  __shared__ float dWs[LAT][SD];
  __shared__ float b1s[HID];
  __shared__ float b2s[LAT*XDm];
  __shared__ float dbs[SD];

  const int tid = threadIdx.x;
  const int b0 = blockIdx.x * BT;

  // weight staging (transpose W1 into [j][k])
  for (int i=tid;i<HID*LAT;i+=THR){ int j = i & (HID-1); int k = i >> 7; W1t[j][k] = W1[k*HID+j]; }
  for (int i=tid;i<LAT*SD;i+=THR)  ((float*)dWs)[i] = decW[i];
  if (tid < HID) b1s[tid] = b1[tid];
  for (int i=tid;i<LAT*XDm;i+=THR) b2s[i] = b2[i];
  if (tid < SD) dbs[tid] = decb[tid];

  // ---- encode z0 = [s(32), a(8), t(1)] @ encW + encb : one (b,l) per thread ----
  {
    const int bb = tid >> 6;         // 0..15
    const int li = tid & 63;         // 0..63
    const float* sb = s + (size_t)(b0+bb)*Lsz*SD;
    const float* ab = a + (size_t)(b0+bb)*Lsz*AD;
    const float tv = t[(size_t)(b0+bb)*Lsz];
    float acc = encb[li];
    #pragma unroll
    for (int k=0;k<SD;k++) acc = fmaf(sb[k], encW[k*LAT+li], acc);
    #pragma unroll
    for (int k=0;k<AD;k++) acc = fmaf(ab[k], encW[(SD+k)*LAT+li], acc);
    acc = fmaf(tv, encW[(SD+AD)*LAT+li], acc);
    zs[bb][li] = acc;
  }
  __syncthreads();

  // ---- decode out[:,0,:] ----
  if (tid < BT*SD){
    const int bb = tid >> 5; const int o = tid & 31;
    float acc = dbs[o];
    #pragma unroll 8
    for (int k=0;k<LAT;k++) acc = fmaf(zs[bb][k], dWs[k][o], acc);
    out[((size_t)(b0+bb)*Lsz + 0)*SD + o] = acc;
  }

  // ---- per-thread ownership: one (l, b) each ----
  const int ol = tid >> 4;    // 0..63
  const int ob = tid & 15;    // 0..15
  float zb = zs[ob][ol];
  float ka = 0.f;

  const int jg = tid >> 4;    // GEMM1: j-pair 2jg, 2jg+1
  const int j0 = 2*jg;
  const int bg = tid & 15;

  const float4* W2p4 = (const float4*)W2p;

  for (int iv=0; iv<NI; iv++){
    // ---- dX(u) for the 5 distinct u values of this interval ----
    if (tid < 5*BT*XDm){
      int ui = tid/(BT*XDm); int r = tid%(BT*XDm); int bb = r/XDm; int x = r%XDm;
      float u = 0.25f*(float)ui;
      int gb = b0+bb;
      float m0 = m_ws[(size_t)iv    *(Bsz*XDm) + (size_t)gb*XDm + x];
      float m1 = m_ws[(size_t)(iv+1)*(Bsz*XDm) + (size_t)gb*XDm + x];
      float xd;
      if (x==0) xd = t[(size_t)gb*Lsz + iv+1] - t[(size_t)gb*Lsz + iv];
      else      xd = a[((size_t)gb*Lsz + iv+1)*AD + x-1] - a[((size_t)gb*Lsz + iv)*AD + x-1];
      float cb = xd - (2.f*m0 + m1)*(1.f/6.f);
      float cc = 0.5f*m0;
      float cd = (m1 - m0)*(1.f/6.f);
      dXs[ui][bb][x] = cb + (2.f*cc)*u + (3.f*cd)*(u*u);
    }

    auto stage = [&](int ui, int mode){
      __syncthreads();                       // zs (and dXs) ready; prev hs readers done
      // GEMM1: h = relu(z @ W1 + b1), 2 j per thread, float4 LDS reads
      {
        float acc0 = b1s[j0], acc1 = b1s[j0+1];
        const float4* z4p = (const float4*)&zs[bg][0];
        const float4* w0p = (const float4*)&W1t[j0][0];
        const float4* w1p = (const float4*)&W1t[j0+1][0];
        #pragma unroll
        for (int k4=0;k4<LAT/4;k4++){
          float4 zv = z4p[k4];
          float4 wa = w0p[k4];
          float4 wb = w1p[k4];
          acc0 = fmaf(zv.x,wa.x,acc0); acc0 = fmaf(zv.y,wa.y,acc0);
          acc0 = fmaf(zv.z,wa.z,acc0); acc0 = fmaf(zv.w,wa.w,acc0);
          acc1 = fmaf(zv.x,wb.x,acc1); acc1 = fmaf(zv.y,wb.y,acc1);
          acc1 = fmaf(zv.z,wb.z,acc1); acc1 = fmaf(zv.w,wb.w,acc1);
        }
        hs[bg][j0]   = fmaxf(acc0, 0.f);
        hs[bg][j0+1] = fmaxf(acc1, 0.f);
      }
      __syncthreads();                       // hs ready
      // GEMM2 (+b2) then contract with dX — one (l,b) per thread
      float v[XDm];
      #pragma unroll
      for (int x=0;x<XDm;x++) v[x] = b2s[ol*XDm+x];
      const float4* hp = (const float4*)&hs[ob][0];
      #pragma unroll 4
      for (int j4=0;j4<HID/4;j4++){
        float4 h4 = hp[j4];
        int b4 = j4*4*192 + ol*3;
        #define W2STEP(HV)                                                     \
        { float4 wa = W2p4[b4]; float4 wb = W2p4[b4+1]; float wc = W2p[(size_t)(b4+2)*4]; \
          v[0]=fmaf(HV,wa.x,v[0]); v[1]=fmaf(HV,wa.y,v[1]);                    \
          v[2]=fmaf(HV,wa.z,v[2]); v[3]=fmaf(HV,wa.w,v[3]);                    \
          v[4]=fmaf(HV,wb.x,v[4]); v[5]=fmaf(HV,wb.y,v[5]);                    \
          v[6]=fmaf(HV,wb.z,v[6]); v[7]=fmaf(HV,wb.w,v[7]);                    \
          v[8]=fmaf(HV,wc,v[8]);  b4 += 192; }
        W2STEP(h4.x) W2STEP(h4.y) W2STEP(h4.z) W2STEP(h4.w)
        #undef W2STEP
      }
      float dz = 0.f;
      #pragma unroll
      for (int x=0;x<XDm;x++) dz = fmaf(v[x], dXs[ui][ob][x], dz);
      // RK4 bookkeeping (h = 0.5)
      if (mode == 0){        ka = dz;
        zs[ob][ol] = zb + 0.25f*dz;
      } else if (mode == 1){ ka = fmaf(2.f, dz, ka);
        zs[ob][ol] = zb + 0.25f*dz;
      } else if (mode == 2){ ka = fmaf(2.f, dz, ka);
        zs[ob][ol] = zb + 0.5f*dz;
      } else {               ka += dz;
        zb = fmaf(0.5f/6.f, ka, zb);
        zs[ob][ol] = zb;
      }
    };

    // substep 0 (u0=0):   u = {0, .25, .25, .5}
    stage(0,0); stage(1,1); stage(1,2); stage(2,3);
    // substep 1 (u0=0.5): u = {.5, .75, .75, 1.0}
    stage(2,0); stage(3,1); stage(3,2); stage(4,3);

    __syncthreads();   // final z in zs
    // ---- decode out[:, iv+1, :] ----
    if (tid < BT*SD){
      const int bb = tid >> 5; const int o = tid & 31;
      float acc = dbs[o];
      #pragma unroll 8
      for (int k=0;k<LAT;k++) acc = fmaf(zs[bb][k], dWs[k][o], acc);
      out[((size_t)(b0+bb)*Lsz + (iv+1))*SD + o] = acc;
    }
  }
}

extern "C" void kernel_launch(void* const* d_in, const int* in_sizes, int n_in,
                              void* d_out, int out_size, void* d_ws, size_t ws_size,
                              hipStream_t stream){
  const float* s    = (const float*)d_in[0];
  const float* a    = (const float*)d_in[1];
  const float* t    = (const float*)d_in[2];
  const float* encW = (const float*)d_in[3];
  const float* encb = (const float*)d_in[4];
  const float* W1   = (const float*)d_in[5];
  const float* b1   = (const float*)d_in[6];
  const float* W2   = (const float*)d_in[7];
  const float* b2   = (const float*)d_in[8];
  const float* decW = (const float*)d_in[9];
  const float* decb = (const float*)d_in[10];
  float* out = (float*)d_out;
  float* ws  = (float*)d_ws;
  float* W2p  = ws;                        // 98,304 floats (384KB)
  float* m_ws = ws + HID*LAT*12;           // 128*4096*9 floats (18.9MB)

  hipLaunchKernelGGL(repack_w2, dim3((HID*LAT*12+255)/256), dim3(256), 0, stream, W2, W2p);
  hipLaunchKernelGGL(spline_kernel, dim3(Bsz*XDm/256), dim3(256), 0, stream, t, a, m_ws);
  hipLaunchKernelGGL(cde_integrate, dim3(Bsz/BT), dim3(THR), 0, stream,
                     s,a,t,encW,encb,W1,b1,b2,decW,decb,W2p,m_ws,out);
}

// Round 3
// 9636.665 us; speedup vs baseline: 4.0245x; 4.0245x over previous
//
#include <hip/hip_runtime.h>

#define Bsz 4096
#define Lsz 128
#define NI  127
#define SD  32
#define AD  8
#define XDm 9
#define LAT 64
#define HID 128
#define BT  16
#define THR 1024

// ---------------- W2 repack: [128][576] -> [j][l][12] (16B-aligned rows of 9+3pad) ----------------
__global__ __launch_bounds__(256) void repack_w2(const float* __restrict__ W2, float* __restrict__ W2p){
  int idx = blockIdx.x*256 + threadIdx.x;
  if (idx >= HID*LAT*12) return;
  int x = idx % 12; int jl = idx / 12; int l = jl % LAT; int j = jl / LAT;
  W2p[idx] = (x < XDm) ? W2[j*(LAT*XDm) + l*XDm + x] : 0.f;
}

// ---------------- Natural cubic spline: Thomas solve per (b,channel) ----------------
__global__ __launch_bounds__(256) void spline_kernel(const float* __restrict__ t,
                                                     const float* __restrict__ a,
                                                     float* __restrict__ m_ws){
  __shared__ float cp_s[126];
  if (threadIdx.x == 0){
    float c = 0.25f; cp_s[0] = c;
    for (int i=1;i<126;i++){ c = 1.0f/(4.0f - c); cp_s[i] = c; }
  }
  __syncthreads();
  int tid = blockIdx.x*256 + threadIdx.x;   // tid = b*9 + c
  int b = tid/XDm, c = tid%XDm;
  float dp[126];
  const float* tb = t + (size_t)b*Lsz;
  const float* ab = a + (size_t)b*Lsz*AD + (c-1);
  float x0 = (c==0)? tb[0] : ab[0];
  float x1 = (c==0)? tb[1] : ab[AD];
  for (int i=0;i<126;i++){
    float x2 = (c==0)? tb[i+2] : ab[(size_t)(i+2)*AD];
    float rhs = 6.0f*(x2 - 2.0f*x1 + x0);
    dp[i] = (i==0)? rhs*0.25f : (rhs - dp[i-1])*cp_s[i];
    x0 = x1; x1 = x2;
  }
  m_ws[tid] = 0.0f;
  m_ws[(size_t)127*(Bsz*XDm) + tid] = 0.0f;
  float mn = 0.0f;
  for (int k=125;k>=0;k--){
    mn = dp[k] - cp_s[k]*mn;
    m_ws[(size_t)(k+1)*(Bsz*XDm) + tid] = mn;
  }
}

// butterfly helper: imm must be a literal at each use site (macro)
#define BFLY(MASK_IMM) { _Pragma("unroll") \
  for (int b_=0;b_<16;b_++) \
    dz[b_] += __int_as_float(__builtin_amdgcn_ds_swizzle(__float_as_int(dz[b_]), MASK_IMM)); }

// ---------------- Persistent RK4 integrator: W2 register-resident, butterfly reduce ----------------
__global__ __launch_bounds__(THR, 4) void cde_integrate(
    const float* __restrict__ s, const float* __restrict__ a, const float* __restrict__ t,
    const float* __restrict__ encW, const float* __restrict__ encb,
    const float* __restrict__ W1, const float* __restrict__ b1,
    const float* __restrict__ b2, const float* __restrict__ decW, const float* __restrict__ decb,
    const float* __restrict__ W2p, const float* __restrict__ m_ws,
    float* __restrict__ out)
{
  __shared__ float W1t[HID][LAT+4];    // [j][k], pad 68
  __shared__ float hs[BT][HID+4];      // [b][j], pad 132
  __shared__ float zs[BT][LAT+4];      // [b][l], pad 68
  __shared__ float dXs[5][BT][12];     // dX at u in {0,.25,.5,.75,1}, 9 used + pad
  __shared__ float bds[BT][LAT+4];     // per-stage bias·dX term
  __shared__ float dWs[LAT][SD];
  __shared__ float b1s[HID];
  __shared__ float b2s[LAT][12];
  __shared__ float dbs[SD];

  const int tid = threadIdx.x;
  const int b0 = blockIdx.x * BT;

  // ---- weight staging ----
  for (int i=tid;i<HID*LAT;i+=THR){ int j = i & (HID-1); int k = i >> 7; W1t[j][k] = W1[k*HID+j]; }
  for (int i=tid;i<LAT*SD;i+=THR)  ((float*)dWs)[i] = decW[i];
  if (tid < HID) b1s[tid] = b1[tid];
  for (int i=tid;i<LAT*12;i+=THR){ int l=i/12, x=i%12; b2s[l][x] = (x<XDm)? b2[l*XDm+x] : 0.f; }
  if (tid < SD) dbs[tid] = decb[tid];

  // ---- W2 -> registers: thread (ol = tid>>4, jg = tid&15) owns j = jg*8..+7 at column ol ----
  const int ol = tid >> 4;    // 0..63 : latent l  (also GEMM1 j-pair index)
  const int jg = tid & 15;    // 0..15 : j-group   (also GEMM1 b, and RK4 b-owner)
  float4 wa[8], wb[8]; float wc[8];
  {
    const float4* W2p4 = (const float4*)W2p;
    #pragma unroll
    for (int jj=0;jj<8;jj++){
      size_t base = ((size_t)(jg*8+jj)*LAT + ol)*3;
      wa[jj] = W2p4[base]; wb[jj] = W2p4[base+1]; wc[jj] = W2p[(base+2)*4];
    }
  }

  // ---- encode z0 ----
  {
    const int bb = tid >> 6;         // 0..15
    const int li = tid & 63;         // 0..63
    const float* sb = s + (size_t)(b0+bb)*Lsz*SD;
    const float* ab = a + (size_t)(b0+bb)*Lsz*AD;
    const float tv = t[(size_t)(b0+bb)*Lsz];
    float acc = encb[li];
    #pragma unroll
    for (int k=0;k<SD;k++) acc = fmaf(sb[k], encW[k*LAT+li], acc);
    #pragma unroll
    for (int k=0;k<AD;k++) acc = fmaf(ab[k], encW[(SD+k)*LAT+li], acc);
    acc = fmaf(tv, encW[(SD+AD)*LAT+li], acc);
    zs[bb][li] = acc;
  }
  __syncthreads();

  // ---- decode out[:,0,:] ----
  if (tid < BT*SD){
    const int bb = tid >> 5; const int o = tid & 31;
    float acc = dbs[o];
    #pragma unroll 8
    for (int k=0;k<LAT;k++) acc = fmaf(zs[bb][k], dWs[k][o], acc);
    out[((size_t)(b0+bb)*Lsz + 0)*SD + o] = acc;
  }

  // RK4 state: this thread owns z(l=ol, b=jg)
  float zb = zs[jg][ol];
  float ka = 0.f;

  for (int iv=0; iv<NI; iv++){
    // ---- dX(u) for the 5 distinct u values of this interval ----
    if (tid < 5*BT*XDm){
      int ui = tid/(BT*XDm); int r = tid%(BT*XDm); int bb = r/XDm; int x = r%XDm;
      float u = 0.25f*(float)ui;
      int gb = b0+bb;
      float m0 = m_ws[(size_t)iv    *(Bsz*XDm) + (size_t)gb*XDm + x];
      float m1 = m_ws[(size_t)(iv+1)*(Bsz*XDm) + (size_t)gb*XDm + x];
      float xd;
      if (x==0) xd = t[(size_t)gb*Lsz + iv+1] - t[(size_t)gb*Lsz + iv];
      else      xd = a[((size_t)gb*Lsz + iv+1)*AD + x-1] - a[((size_t)gb*Lsz + iv)*AD + x-1];
      float cb = xd - (2.f*m0 + m1)*(1.f/6.f);
      float cc = 0.5f*m0;
      float cd = (m1 - m0)*(1.f/6.f);
      dXs[ui][bb][x] = cb + (2.f*cc)*u + (3.f*cd)*(u*u);
    }

    for (int st=0; st<8; st++){
      const int ui = (st+1)>>1;      // {0,1,1,2,2,3,3,4}
      const int mode = st & 3;       // {0,1,2,3,0,1,2,3}
      __syncthreads();               // zs, dXs ready; prev hs/bds readers done

      // ---- GEMM1: h = relu(z @ W1 + b1); thread (jp=ol, b=jg), 2 j outputs ----
      {
        const int j0 = 2*ol;
        float acc0 = b1s[j0], acc1 = b1s[j0+1];
        const float4* z4 = (const float4*)&zs[jg][0];
        const float4* w0 = (const float4*)&W1t[j0][0];
        const float4* w1 = (const float4*)&W1t[j0+1][0];
        #pragma unroll
        for (int k4=0;k4<LAT/4;k4++){
          float4 zv = z4[k4]; float4 u0 = w0[k4]; float4 u1 = w1[k4];
          acc0 = fmaf(zv.x,u0.x,acc0); acc0 = fmaf(zv.y,u0.y,acc0);
          acc0 = fmaf(zv.z,u0.z,acc0); acc0 = fmaf(zv.w,u0.w,acc0);
          acc1 = fmaf(zv.x,u1.x,acc1); acc1 = fmaf(zv.y,u1.y,acc1);
          acc1 = fmaf(zv.z,u1.z,acc1); acc1 = fmaf(zv.w,u1.w,acc1);
        }
        hs[jg][j0]   = fmaxf(acc0, 0.f);
        hs[jg][j0+1] = fmaxf(acc1, 0.f);
      }
      // ---- bias·dX for this stage: bds[b][l] = sum_x b2[l][x]*dX[b][x] ----
      {
        const int bb = tid >> 6; const int ll = tid & 63;
        float sacc = 0.f;
        #pragma unroll
        for (int x=0;x<XDm;x++) sacc = fmaf(b2s[ll][x], dXs[ui][bb][x], sacc);
        bds[bb][ll] = sacc;
      }
      __syncthreads();               // hs, bds ready

      // ---- GEMM2 partials from register-resident W2; one partial per b ----
      float dz[16];
      #pragma unroll
      for (int b=0;b<16;b++){
        float4 dxa = *(const float4*)&dXs[ui][b][0];
        float4 dxb = *(const float4*)&dXs[ui][b][4];
        float  dxc = dXs[ui][b][8];
        float4 h0  = *(const float4*)&hs[b][jg*8];
        float4 h1  = *(const float4*)&hs[b][jg*8+4];
        float acc = 0.f;
        #define STEP(JJ, HV) { \
          float wd = fmaf(wa[JJ].x,dxa.x, fmaf(wa[JJ].y,dxa.y, fmaf(wa[JJ].z,dxa.z, fmaf(wa[JJ].w,dxa.w, \
                     fmaf(wb[JJ].x,dxb.x, fmaf(wb[JJ].y,dxb.y, fmaf(wb[JJ].z,dxb.z, fmaf(wb[JJ].w,dxb.w, \
                     wc[JJ]*dxc)))))))); \
          acc = fmaf(HV, wd, acc); }
        STEP(0,h0.x) STEP(1,h0.y) STEP(2,h0.z) STEP(3,h0.w)
        STEP(4,h1.x) STEP(5,h1.y) STEP(6,h1.z) STEP(7,h1.w)
        #undef STEP
        dz[b] = acc;
      }
      // ---- butterfly reduce over the 16 jg lanes (intra-wave; jg = lane&15) ----
      BFLY(0x041F) BFLY(0x081F) BFLY(0x101F) BFLY(0x201F)
      // ---- select own b, add bias term ----
      float dzm = dz[0];
      #pragma unroll
      for (int b=1;b<16;b++) dzm = (jg==b)? dz[b] : dzm;
      dzm += bds[jg][ol];
      // ---- RK4 bookkeeping (h = 0.5) ----
      if (mode == 0){        ka = dzm;
        zs[jg][ol] = zb + 0.25f*dzm;
      } else if (mode == 1){ ka = fmaf(2.f, dzm, ka);
        zs[jg][ol] = zb + 0.25f*dzm;
      } else if (mode == 2){ ka = fmaf(2.f, dzm, ka);
        zs[jg][ol] = zb + 0.5f*dzm;
      } else {               ka += dzm;
        zb = fmaf(0.5f/6.f, ka, zb);
        zs[jg][ol] = zb;
      }
    }

    __syncthreads();   // final z in zs
    // ---- decode out[:, iv+1, :] ----
    if (tid < BT*SD){
      const int bb = tid >> 5; const int o = tid & 31;
      float acc = dbs[o];
      #pragma unroll 8
      for (int k=0;k<LAT;k++) acc = fmaf(zs[bb][k], dWs[k][o], acc);
      out[((size_t)(b0+bb)*Lsz + (iv+1))*SD + o] = acc;
    }
  }
}

extern "C" void kernel_launch(void* const* d_in, const int* in_sizes, int n_in,
                              void* d_out, int out_size, void* d_ws, size_t ws_size,
                              hipStream_t stream){
  const float* s    = (const float*)d_in[0];
  const float* a    = (const float*)d_in[1];
  const float* t    = (const float*)d_in[2];
  const float* encW = (const float*)d_in[3];
  const float* encb = (const float*)d_in[4];
  const float* W1   = (const float*)d_in[5];
  const float* b1   = (const float*)d_in[6];
  const float* W2   = (const float*)d_in[7];
  const float* b2   = (const float*)d_in[8];
  const float* decW = (const float*)d_in[9];
  const float* decb = (const float*)d_in[10];
  float* out = (float*)d_out;
  float* ws  = (float*)d_ws;
  float* W2p  = ws;                        // 98,304 floats (384KB)
  float* m_ws = ws + HID*LAT*12;           // 128*4096*9 floats (18.9MB)

  hipLaunchKernelGGL(repack_w2, dim3((HID*LAT*12+255)/256), dim3(256), 0, stream, W2, W2p);
  hipLaunchKernelGGL(spline_kernel, dim3(Bsz*XDm/256), dim3(256), 0, stream, t, a, m_ws);
  hipLaunchKernelGGL(cde_integrate, dim3(Bsz/BT), dim3(THR), 0, stream,
                     s,a,t,encW,encb,W1,b1,b2,decW,decb,W2p,m_ws,out);
}

// Round 4
// 9054.332 us; speedup vs baseline: 4.2833x; 1.0643x over previous
//
#include <hip/hip_runtime.h>

#define Bsz 4096
#define Lsz 128
#define NI  127
#define SD  32
#define AD  8
#define XDm 9
#define LAT 64
#define HID 128
#define BT  16
#define THR 1024

// ---------------- W2 repack: [128][576] -> [j][l][12] (16B-aligned rows of 9+3pad) ----------------
__global__ __launch_bounds__(256) void repack_w2(const float* __restrict__ W2, float* __restrict__ W2p){
  int idx = blockIdx.x*256 + threadIdx.x;
  if (idx >= HID*LAT*12) return;
  int x = idx % 12; int jl = idx / 12; int l = jl % LAT; int j = jl / LAT;
  W2p[idx] = (x < XDm) ? W2[j*(LAT*XDm) + l*XDm + x] : 0.f;
}

// ---------------- Natural cubic spline: Thomas solve per (b,channel) ----------------
__global__ __launch_bounds__(256) void spline_kernel(const float* __restrict__ t,
                                                     const float* __restrict__ a,
                                                     float* __restrict__ m_ws){
  __shared__ float cp_s[126];
  if (threadIdx.x == 0){
    float c = 0.25f; cp_s[0] = c;
    for (int i=1;i<126;i++){ c = 1.0f/(4.0f - c); cp_s[i] = c; }
  }
  __syncthreads();
  int tid = blockIdx.x*256 + threadIdx.x;   // tid = b*9 + c
  int b = tid/XDm, c = tid%XDm;
  float dp[126];
  const float* tb = t + (size_t)b*Lsz;
  const float* ab = a + (size_t)b*Lsz*AD + (c-1);
  float x0 = (c==0)? tb[0] : ab[0];
  float x1 = (c==0)? tb[1] : ab[AD];
  for (int i=0;i<126;i++){
    float x2 = (c==0)? tb[i+2] : ab[(size_t)(i+2)*AD];
    float rhs = 6.0f*(x2 - 2.0f*x1 + x0);
    dp[i] = (i==0)? rhs*0.25f : (rhs - dp[i-1])*cp_s[i];
    x0 = x1; x1 = x2;
  }
  m_ws[tid] = 0.0f;
  m_ws[(size_t)127*(Bsz*XDm) + tid] = 0.0f;
  float mn = 0.0f;
  for (int k=125;k>=0;k--){
    mn = dp[k] - cp_s[k]*mn;
    m_ws[(size_t)(k+1)*(Bsz*XDm) + tid] = mn;
  }
}

// cross-lane helpers
#define DPP_XOR1(v) __int_as_float(__builtin_amdgcn_mov_dpp(__float_as_int(v), 0xB1, 0xF, 0xF, true))
#define DPP_XOR2(v) __int_as_float(__builtin_amdgcn_mov_dpp(__float_as_int(v), 0x4E, 0xF, 0xF, true))
#define SWZ_XOR4(v) __int_as_float(__builtin_amdgcn_ds_swizzle(__float_as_int(v), 0x101F))
#define SWZ_XOR8(v) __int_as_float(__builtin_amdgcn_ds_swizzle(__float_as_int(v), 0x201F))

// hs layout: [b][blk*12 + jj], row stride 196 floats (2-way banks on both r/w)
#define HROW 196

// ---------------- Persistent RK4 integrator ----------------
__global__ __launch_bounds__(THR, 4) void cde_integrate(
    const float* __restrict__ s, const float* __restrict__ a, const float* __restrict__ t,
    const float* __restrict__ encW, const float* __restrict__ encb,
    const float* __restrict__ W1, const float* __restrict__ b1,
    const float* __restrict__ b2, const float* __restrict__ decW, const float* __restrict__ decb,
    const float* __restrict__ W2p, const float* __restrict__ m_ws,
    float* __restrict__ out)
{
  __shared__ float W1t[HID][LAT+4];    // [j][k], pad 68
  __shared__ float hs[BT][HROW];       // [b][swizzled j]
  __shared__ float zs[BT][LAT+4];      // [b][l]
  __shared__ float dXs[5][BT][12];     // dX at u in {0,.25,.5,.75,1}
  __shared__ float bds[BT][LAT+4];     // per-stage bias·dX
  __shared__ float dWs[LAT][SD];
  __shared__ float b1s[HID];
  __shared__ float b2s[LAT][12];
  __shared__ float dbs[SD];

  const int tid = threadIdx.x;
  const int b0 = blockIdx.x * BT;

  // ---- weight staging ----
  for (int i=tid;i<HID*LAT;i+=THR){ int j = i & (HID-1); int k = i >> 7; W1t[j][k] = W1[k*HID+j]; }
  for (int i=tid;i<LAT*SD;i+=THR)  ((float*)dWs)[i] = decW[i];
  if (tid < HID) b1s[tid] = b1[tid];
  for (int i=tid;i<LAT*12;i+=THR){ int l=i/12, x=i%12; b2s[l][x] = (x<XDm)? b2[l*XDm+x] : 0.f; }
  if (tid < SD) dbs[tid] = decb[tid];

  // ---- encode z0 ----
  {
    const int bb = tid >> 6;
    const int li = tid & 63;
    const float* sb = s + (size_t)(b0+bb)*Lsz*SD;
    const float* ab = a + (size_t)(b0+bb)*Lsz*AD;
    const float tv = t[(size_t)(b0+bb)*Lsz];
    float acc = encb[li];
    #pragma unroll
    for (int k=0;k<SD;k++) acc = fmaf(sb[k], encW[k*LAT+li], acc);
    #pragma unroll
    for (int k=0;k<AD;k++) acc = fmaf(ab[k], encW[(SD+k)*LAT+li], acc);
    acc = fmaf(tv, encW[(SD+AD)*LAT+li], acc);
    zs[bb][li] = acc;
  }
  __syncthreads();

  // ---- decode out[:,0,:] ----
  if (tid < BT*SD){
    const int bb = tid >> 5; const int o = tid & 31;
    float acc = dbs[o];
    #pragma unroll 8
    for (int k=0;k<LAT;k++) acc = fmaf(zs[bb][k], dWs[k][o], acc);
    out[((size_t)(b0+bb)*Lsz + 0)*SD + o] = acc;
  }

  // ---- ownership: thread (ol = tid>>4, jg = tid&15) ----
  const int ol = tid >> 4;
  const int jg = tid & 15;

  // ---- W2 -> registers (j = jg*8..+7, column ol), pinned via asm ----
  float4 wa[8], wb[8]; float wc[8];
  {
    const float4* W2p4 = (const float4*)W2p;
    #pragma unroll
    for (int jj=0;jj<8;jj++){
      size_t base = ((size_t)(jg*8+jj)*LAT + ol)*3;
      wa[jj] = W2p4[base]; wb[jj] = W2p4[base+1]; wc[jj] = W2p[(base+2)*4];
    }
    #pragma unroll
    for (int jj=0;jj<8;jj++){
      asm volatile("" : "+v"(wa[jj].x), "+v"(wa[jj].y), "+v"(wa[jj].z), "+v"(wa[jj].w),
                        "+v"(wb[jj].x), "+v"(wb[jj].y), "+v"(wb[jj].z), "+v"(wb[jj].w),
                        "+v"(wc[jj]));
    }
  }

  // RK4 state: thread owns z(l=ol, b=jg)
  float zb = zs[jg][ol];
  float ka = 0.f;

  for (int iv=0; iv<NI; iv++){
    // ---- dX(u) at the 5 distinct u of this interval ----
    if (tid < 5*BT*XDm){
      int ui = tid/(BT*XDm); int r = tid%(BT*XDm); int bb = r/XDm; int x = r%XDm;
      float u = 0.25f*(float)ui;
      int gb = b0+bb;
      float m0 = m_ws[(size_t)iv    *(Bsz*XDm) + (size_t)gb*XDm + x];
      float m1 = m_ws[(size_t)(iv+1)*(Bsz*XDm) + (size_t)gb*XDm + x];
      float xd;
      if (x==0) xd = t[(size_t)gb*Lsz + iv+1] - t[(size_t)gb*Lsz + iv];
      else      xd = a[((size_t)gb*Lsz + iv+1)*AD + x-1] - a[((size_t)gb*Lsz + iv)*AD + x-1];
      float cb = xd - (2.f*m0 + m1)*(1.f/6.f);
      float cc = 0.5f*m0;
      float cd = (m1 - m0)*(1.f/6.f);
      dXs[ui][bb][x] = cb + (2.f*cc)*u + (3.f*cd)*(u*u);
    }

    for (int st=0; st<8; st++){
      const int ui = (st+1)>>1;      // {0,1,1,2,2,3,3,4}
      const int mode = st & 3;
      __syncthreads();               // zs,dXs readable; prev hs/bds readers done

      // ---- GEMM1: h[jg][2ol..2ol+1] = relu(z@W1+b1) ----
      {
        const int j0 = 2*ol;
        float acc0 = b1s[j0], acc1 = b1s[j0+1];
        const float4* z4 = (const float4*)&zs[jg][0];
        const float4* w0 = (const float4*)&W1t[j0][0];
        const float4* w1 = (const float4*)&W1t[j0+1][0];
        #pragma unroll
        for (int k4=0;k4<LAT/4;k4++){
          float4 zv = z4[k4]; float4 u0 = w0[k4]; float4 u1 = w1[k4];
          acc0 = fmaf(zv.x,u0.x,acc0); acc0 = fmaf(zv.y,u0.y,acc0);
          acc0 = fmaf(zv.z,u0.z,acc0); acc0 = fmaf(zv.w,u0.w,acc0);
          acc1 = fmaf(zv.x,u1.x,acc1); acc1 = fmaf(zv.y,u1.y,acc1);
          acc1 = fmaf(zv.z,u1.z,acc1); acc1 = fmaf(zv.w,u1.w,acc1);
        }
        float2 hv; hv.x = fmaxf(acc0,0.f); hv.y = fmaxf(acc1,0.f);
        *(float2*)&hs[jg][(j0>>3)*12 + (j0&7)] = hv;
      }
      // ---- bias·dX: wave w owns b=w; bds[w][lane] ----
      {
        const int w = tid >> 6; const int ll = tid & 63;
        const float4 ba = *(const float4*)&b2s[ll][0];
        const float4 bb4 = *(const float4*)&b2s[ll][4];
        const float  bc = b2s[ll][8];
        const float4 da = *(const float4*)&dXs[ui][w][0];
        const float4 db = *(const float4*)&dXs[ui][w][4];
        const float  dc = dXs[ui][w][8];
        float sacc = bc*dc;
        sacc = fmaf(ba.x,da.x, fmaf(ba.y,da.y, fmaf(ba.z,da.z, fmaf(ba.w,da.w, sacc))));
        sacc = fmaf(bb4.x,db.x, fmaf(bb4.y,db.y, fmaf(bb4.z,db.z, fmaf(bb4.w,db.w, sacc))));
        bds[w][ll] = sacc;
      }
      __syncthreads();               // hs, bds ready

      // ---- GEMM2 partials (register W2) in 2 batches of 8 b + recursive-halving reduce ----
      auto gemm2_batch = [&](const int bb0)->float {
        float dz[8];
        #pragma unroll
        for (int i=0;i<8;i++){
          const int b = bb0 + i;
          const float4 dxa = *(const float4*)&dXs[ui][b][0];
          const float4 dxb = *(const float4*)&dXs[ui][b][4];
          const float  dxc = dXs[ui][b][8];
          const float4 h0 = *(const float4*)&hs[b][jg*12];
          const float4 h1 = *(const float4*)&hs[b][jg*12+4];
          float acc = 0.f;
          #define STEP(JJ, HV) { \
            float wd = fmaf(wa[JJ].x,dxa.x, fmaf(wa[JJ].y,dxa.y, fmaf(wa[JJ].z,dxa.z, fmaf(wa[JJ].w,dxa.w, \
                       fmaf(wb[JJ].x,dxb.x, fmaf(wb[JJ].y,dxb.y, fmaf(wb[JJ].z,dxb.z, fmaf(wb[JJ].w,dxb.w, \
                       wc[JJ]*dxc)))))))); \
            acc = fmaf(HV, wd, acc); }
          STEP(0,h0.x) STEP(1,h0.y) STEP(2,h0.z) STEP(3,h0.w)
          STEP(4,h1.x) STEP(5,h1.y) STEP(6,h1.z) STEP(7,h1.w)
          #undef STEP
          dz[i] = acc;
        }
        // round xor1 (DPP): keep b with (b&1)==(jg&1)
        const bool g1 = (jg&1);
        float nd[4];
        #pragma unroll
        for (int i=0;i<4;i++){
          float lo = dz[2*i], hi = dz[2*i+1];
          float send = g1 ? lo : hi;
          float recv = DPP_XOR1(send);
          float keep = g1 ? hi : lo;
          nd[i] = keep + recv;
        }
        // round xor2 (DPP)
        const bool g2 = (jg&2);
        float md[2];
        #pragma unroll
        for (int i=0;i<2;i++){
          float lo = nd[2*i], hi = nd[2*i+1];
          float send = g2 ? lo : hi;
          float recv = DPP_XOR2(send);
          float keep = g2 ? hi : lo;
          md[i] = keep + recv;
        }
        // round xor4 (ds_swizzle)
        const bool g4 = (jg&4);
        {
          float lo = md[0], hi = md[1];
          float send = g4 ? lo : hi;
          float recv = SWZ_XOR4(send);
          float keep = g4 ? hi : lo;
          float r = keep + recv;
          // round xor8: combine the two j-halves (both lanes end with full sum)
          return r + SWZ_XOR8(r);
        }
      };
      const float totA = gemm2_batch(0);
      const float totB = gemm2_batch(8);
      float dzm = ((jg&8)? totB : totA) + bds[jg][ol];

      // ---- RK4 bookkeeping (h = 0.5) ----
      if (mode == 0){        ka = dzm;
        zs[jg][ol] = zb + 0.25f*dzm;
      } else if (mode == 1){ ka = fmaf(2.f, dzm, ka);
        zs[jg][ol] = zb + 0.25f*dzm;
      } else if (mode == 2){ ka = fmaf(2.f, dzm, ka);
        zs[jg][ol] = zb + 0.5f*dzm;
      } else {               ka += dzm;
        zb = fmaf(0.5f/6.f, ka, zb);
        zs[jg][ol] = zb;
      }
    }

    __syncthreads();   // final z in zs
    // ---- decode out[:, iv+1, :] ----
    if (tid < BT*SD){
      const int bb = tid >> 5; const int o = tid & 31;
      float acc = dbs[o];
      #pragma unroll 8
      for (int k=0;k<LAT;k++) acc = fmaf(zs[bb][k], dWs[k][o], acc);
      out[((size_t)(b0+bb)*Lsz + (iv+1))*SD + o] = acc;
    }
  }
}

extern "C" void kernel_launch(void* const* d_in, const int* in_sizes, int n_in,
                              void* d_out, int out_size, void* d_ws, size_t ws_size,
                              hipStream_t stream){
  const float* s    = (const float*)d_in[0];
  const float* a    = (const float*)d_in[1];
  const float* t    = (const float*)d_in[2];
  const float* encW = (const float*)d_in[3];
  const float* encb = (const float*)d_in[4];
  const float* W1   = (const float*)d_in[5];
  const float* b1   = (const float*)d_in[6];
  const float* W2   = (const float*)d_in[7];
  const float* b2   = (const float*)d_in[8];
  const float* decW = (const float*)d_in[9];
  const float* decb = (const float*)d_in[10];
  float* out = (float*)d_out;
  float* ws  = (float*)d_ws;
  float* W2p  = ws;                        // 98,304 floats (384KB)
  float* m_ws = ws + HID*LAT*12;           // 128*4096*9 floats (18.9MB)

  hipLaunchKernelGGL(repack_w2, dim3((HID*LAT*12+255)/256), dim3(256), 0, stream, W2, W2p);
  hipLaunchKernelGGL(spline_kernel, dim3(Bsz*XDm/256), dim3(256), 0, stream, t, a, m_ws);
  hipLaunchKernelGGL(cde_integrate, dim3(Bsz/BT), dim3(THR), 0, stream,
                     s,a,t,encW,encb,W1,b1,b2,decW,decb,W2p,m_ws,out);
}

// Round 5
// 8408.597 us; speedup vs baseline: 4.6123x; 1.0768x over previous
//
#include <hip/hip_runtime.h>

#define Bsz 4096
#define Lsz 128
#define NI  127
#define SD  32
#define AD  8
#define LAT 64
#define HID 128
#define BT  16
#define THR 1024

// ---------------- W2 repack ----------------
// W2 [128][64][9] -> W2p8 [j][l][8] (channels 1..8, 32B rows) + W2c0 [j][l] (channel 0)
__global__ __launch_bounds__(256) void repack_w2(const float* __restrict__ W2,
                                                 float* __restrict__ W2p8,
                                                 float* __restrict__ W2c0){
  int idx = blockIdx.x*256 + threadIdx.x;
  if (idx < HID*LAT*8){
    int x = idx & 7; int jl = idx >> 3; int l = jl & 63; int j = jl >> 6;
    W2p8[idx] = W2[(j*LAT + l)*9 + x + 1];
  } else if (idx < HID*LAT*9){
    int jl = idx - HID*LAT*8;
    W2c0[jl] = W2[(size_t)jl*9];
  }
}

// ---------------- Natural cubic spline: channels 1..8 only (t-channel is exactly linear) ----------------
// m_ws layout [i][b][8], i=0..127
__global__ __launch_bounds__(256) void spline_kernel(const float* __restrict__ a,
                                                     float* __restrict__ m_ws){
  __shared__ float cp_s[126];
  if (threadIdx.x == 0){
    float c = 0.25f; cp_s[0] = c;
    for (int i=1;i<126;i++){ c = 1.0f/(4.0f - c); cp_s[i] = c; }
  }
  __syncthreads();
  int tid = blockIdx.x*256 + threadIdx.x;   // tid = b*8 + c8, 32768 threads
  int b = tid >> 3, c8 = tid & 7;
  float dp[126];
  const float* ab = a + (size_t)b*Lsz*AD + c8;
  float x0 = ab[0];
  float x1 = ab[AD];
  for (int i=0;i<126;i++){
    float x2 = ab[(size_t)(i+2)*AD];
    float rhs = 6.0f*(x2 - 2.0f*x1 + x0);
    dp[i] = (i==0)? rhs*0.25f : (rhs - dp[i-1])*cp_s[i];
    x0 = x1; x1 = x2;
  }
  m_ws[tid] = 0.0f;                                   // m[0]
  m_ws[((size_t)127*Bsz)*8 + tid] = 0.0f;             // m[127]
  float mn = 0.0f;
  for (int k=125;k>=0;k--){
    mn = dp[k] - cp_s[k]*mn;
    m_ws[((size_t)(k+1)*Bsz)*8 + tid] = mn;
  }
}

// cross-lane helpers
#define DPP_XOR1(v) __int_as_float(__builtin_amdgcn_mov_dpp(__float_as_int(v), 0xB1, 0xF, 0xF, true))
#define DPP_XOR2(v) __int_as_float(__builtin_amdgcn_mov_dpp(__float_as_int(v), 0x4E, 0xF, 0xF, true))
#define SWZ_XOR4(v) __int_as_float(__builtin_amdgcn_ds_swizzle(__float_as_int(v), 0x101F))
#define SWZ_XOR8(v) __int_as_float(__builtin_amdgcn_ds_swizzle(__float_as_int(v), 0x201F))

#define HROW 132   // hs row stride (floats): 2-way banks on write & read

// ---------------- Persistent RK4 integrator ----------------
__attribute__((amdgpu_waves_per_eu(4,4)))
__global__ __launch_bounds__(THR) void cde_integrate(
    const float* __restrict__ s, const float* __restrict__ a, const float* __restrict__ t,
    const float* __restrict__ encW, const float* __restrict__ encb,
    const float* __restrict__ W1, const float* __restrict__ b1,
    const float* __restrict__ b2, const float* __restrict__ decW, const float* __restrict__ decb,
    const float* __restrict__ W2p8, const float* __restrict__ W2c0, const float* __restrict__ m_ws,
    float* __restrict__ out)
{
  __shared__ float W1t[HID][LAT+4];    // [j][k], pad 68
  __shared__ float hs[BT][HROW];       // [b][j]
  __shared__ float zs[BT][LAT+4];      // [b][l]
  __shared__ float dXs[5][BT][8];      // dX channels 1..8 at u in {0,.25,.5,.75,1}
  __shared__ float dWs[LAT][SD];
  __shared__ float dbs[SD];

  const int tid = threadIdx.x;
  const int b0 = blockIdx.x * BT;

  // ---- weight staging ----
  for (int i=tid;i<HID*LAT;i+=THR){ int j = i & (HID-1); int k = i >> 7; W1t[j][k] = W1[k*HID+j]; }
  for (int i=tid;i<LAT*SD;i+=THR)  ((float*)dWs)[i] = decW[i];
  if (tid < SD) dbs[tid] = decb[tid];

  // ---- ownership: thread (ol = tid>>4, jg = tid&15) ----
  const int ol = tid >> 4;
  const int jg = tid & 15;

  // ---- persistent registers: W2 slice, b2 column, b1 pair ----
  float4 wa[8], wb[8]; float wc0[8];
  {
    #pragma unroll
    for (int jj=0;jj<8;jj++){
      const int j = jg*8 + jj;
      const float4* p = (const float4*)&W2p8[((size_t)j*LAT + ol)*8];
      wa[jj] = p[0]; wb[jj] = p[1];
      wc0[jj] = W2c0[j*LAT + ol];
    }
    #pragma unroll
    for (int jj=0;jj<8;jj++){
      asm volatile("" : "+v"(wa[jj].x), "+v"(wa[jj].y), "+v"(wa[jj].z), "+v"(wa[jj].w),
                        "+v"(wb[jj].x), "+v"(wb[jj].y), "+v"(wb[jj].z), "+v"(wb[jj].w),
                        "+v"(wc0[jj]));
    }
  }
  float4 b2a, b2b; float b2c0;
  {
    const float* bp = b2 + ol*9;
    b2c0 = bp[0];
    b2a.x = bp[1]; b2a.y = bp[2]; b2a.z = bp[3]; b2a.w = bp[4];
    b2b.x = bp[5]; b2b.y = bp[6]; b2b.z = bp[7]; b2b.w = bp[8];
  }
  const float b1r0 = b1[2*ol], b1r1 = b1[2*ol+1];

  // ---- encode z0 ----
  {
    const int bb = tid >> 6;
    const int li = tid & 63;
    const float* sb = s + (size_t)(b0+bb)*Lsz*SD;
    const float* ab = a + (size_t)(b0+bb)*Lsz*AD;
    const float tv = t[(size_t)(b0+bb)*Lsz];
    float acc = encb[li];
    #pragma unroll
    for (int k=0;k<SD;k++) acc = fmaf(sb[k], encW[k*LAT+li], acc);
    #pragma unroll
    for (int k=0;k<AD;k++) acc = fmaf(ab[k], encW[(SD+k)*LAT+li], acc);
    acc = fmaf(tv, encW[(SD+AD)*LAT+li], acc);
    zs[bb][li] = acc;
  }
  __syncthreads();

  // ---- decode out[:,0,:] ----
  if (tid < BT*SD){
    const int bb = tid >> 5; const int o = tid & 31;
    float acc = dbs[o];
    #pragma unroll 8
    for (int k=0;k<LAT;k++) acc = fmaf(zs[bb][k], dWs[k][o], acc);
    out[((size_t)(b0+bb)*Lsz + 0)*SD + o] = acc;
  }

  // RK4 state: thread owns z(l=ol, b=jg)
  float zb = zs[jg][ol];
  float ka = 0.f;

  for (int iv=0; iv<NI; iv++){
    // ---- dX(u) channels 1..8 at the 5 distinct u of this interval ----
    if (tid < 5*BT*8){
      int ui = tid >> 7; int r = tid & 127; int bb = r >> 3; int x8 = r & 7;
      float u = 0.25f*(float)ui;
      int gb = b0+bb;
      float m0 = m_ws[((size_t)iv    *Bsz + gb)*8 + x8];
      float m1 = m_ws[((size_t)(iv+1)*Bsz + gb)*8 + x8];
      float xd = a[((size_t)gb*Lsz + iv+1)*AD + x8] - a[((size_t)gb*Lsz + iv)*AD + x8];
      float cb = xd - (2.f*m0 + m1)*(1.f/6.f);
      float cc = 0.5f*m0;
      float cd = (m1 - m0)*(1.f/6.f);
      dXs[ui][bb][x8] = cb + (2.f*cc)*u + (3.f*cd)*(u*u);
    }

    for (int st=0; st<8; st++){
      const int ui = (st+1)>>1;      // {0,1,1,2,2,3,3,4}
      const int mode = st & 3;
      __syncthreads();               // zs, dXs readable; prev hs readers done

      // ---- GEMM1: h[jg][2ol..2ol+1] = relu(z @ W1 + b1) ----
      {
        const int j0 = 2*ol;
        float acc0 = b1r0, acc1 = b1r1;
        const float4* z4 = (const float4*)&zs[jg][0];
        const float4* w0 = (const float4*)&W1t[j0][0];
        const float4* w1 = (const float4*)&W1t[j0+1][0];
        #pragma unroll
        for (int k4=0;k4<LAT/4;k4++){
          float4 zv = z4[k4]; float4 u0 = w0[k4]; float4 u1 = w1[k4];
          acc0 = fmaf(zv.x,u0.x,acc0); acc0 = fmaf(zv.y,u0.y,acc0);
          acc0 = fmaf(zv.z,u0.z,acc0); acc0 = fmaf(zv.w,u0.w,acc0);
          acc1 = fmaf(zv.x,u1.x,acc1); acc1 = fmaf(zv.y,u1.y,acc1);
          acc1 = fmaf(zv.z,u1.z,acc1); acc1 = fmaf(zv.w,u1.w,acc1);
        }
        float2 hv; hv.x = fmaxf(acc0,0.f); hv.y = fmaxf(acc1,0.f);
        *(float2*)&hs[jg][j0] = hv;
      }
      __syncthreads();               // hs ready

      // ---- GEMM2 partials (register W2, 8-ch dX + constant t-channel) ----
      auto gemm2_batch = [&](const int bb0)->float {
        float dz[8];
        #pragma unroll
        for (int i=0;i<8;i++){
          const int b = bb0 + i;
          const float4 dxa = *(const float4*)&dXs[ui][b][0];
          const float4 dxb = *(const float4*)&dXs[ui][b][4];
          const float4 h0 = *(const float4*)&hs[b][jg*8];
          const float4 h1 = *(const float4*)&hs[b][jg*8+4];
          float acc = 0.f;
          #define STEP(JJ, HV) { \
            float wd = fmaf(wa[JJ].x,dxa.x, fmaf(wa[JJ].y,dxa.y, fmaf(wa[JJ].z,dxa.z, fmaf(wa[JJ].w,dxa.w, \
                       fmaf(wb[JJ].x,dxb.x, fmaf(wb[JJ].y,dxb.y, fmaf(wb[JJ].z,dxb.z, fmaf(wb[JJ].w,dxb.w, \
                       wc0[JJ])))))))); \
            acc = fmaf(HV, wd, acc); }
          STEP(0,h0.x) STEP(1,h0.y) STEP(2,h0.z) STEP(3,h0.w)
          STEP(4,h1.x) STEP(5,h1.y) STEP(6,h1.z) STEP(7,h1.w)
          #undef STEP
          dz[i] = acc;
        }
        // xor1 (DPP)
        const bool g1 = (jg&1);
        float nd[4];
        #pragma unroll
        for (int i=0;i<4;i++){
          float lo = dz[2*i], hi = dz[2*i+1];
          float send = g1 ? lo : hi;
          float recv = DPP_XOR1(send);
          float keep = g1 ? hi : lo;
          nd[i] = keep + recv;
        }
        // xor2 (DPP)
        const bool g2 = (jg&2);
        float md[2];
        #pragma unroll
        for (int i=0;i<2;i++){
          float lo = nd[2*i], hi = nd[2*i+1];
          float send = g2 ? lo : hi;
          float recv = DPP_XOR2(send);
          float keep = g2 ? hi : lo;
          md[i] = keep + recv;
        }
        // xor4 + xor8 (ds_swizzle)
        const bool g4 = (jg&4);
        float lo = md[0], hi = md[1];
        float send = g4 ? lo : hi;
        float recv = SWZ_XOR4(send);
        float keep = g4 ? hi : lo;
        float r = keep + recv;
        return r + SWZ_XOR8(r);
      };
      const float totA = gemm2_batch(0);
      const float totB = gemm2_batch(8);

      // ---- bias term from registers: b2[ol]·dX[jg] (+ const channel) ----
      float bias;
      {
        const float4 dja = *(const float4*)&dXs[ui][jg][0];
        const float4 djb = *(const float4*)&dXs[ui][jg][4];
        bias = fmaf(b2a.x,dja.x, fmaf(b2a.y,dja.y, fmaf(b2a.z,dja.z, fmaf(b2a.w,dja.w,
               fmaf(b2b.x,djb.x, fmaf(b2b.y,djb.y, fmaf(b2b.z,djb.z, fmaf(b2b.w,djb.w, b2c0))))))));
      }
      float dzm = ((jg&8)? totB : totA) + bias;

      // ---- RK4 bookkeeping (h = 0.5) ----
      if (mode == 0){        ka = dzm;
        zs[jg][ol] = zb + 0.25f*dzm;
      } else if (mode == 1){ ka = fmaf(2.f, dzm, ka);
        zs[jg][ol] = zb + 0.25f*dzm;
      } else if (mode == 2){ ka = fmaf(2.f, dzm, ka);
        zs[jg][ol] = zb + 0.5f*dzm;
      } else {               ka += dzm;
        zb = fmaf(0.5f/6.f, ka, zb);
        zs[jg][ol] = zb;
      }
    }

    __syncthreads();   // final z in zs
    // ---- decode out[:, iv+1, :] ----
    if (tid < BT*SD){
      const int bb = tid >> 5; const int o = tid & 31;
      float acc = dbs[o];
      #pragma unroll 8
      for (int k=0;k<LAT;k++) acc = fmaf(zs[bb][k], dWs[k][o], acc);
      out[((size_t)(b0+bb)*Lsz + (iv+1))*SD + o] = acc;
    }
  }
}

extern "C" void kernel_launch(void* const* d_in, const int* in_sizes, int n_in,
                              void* d_out, int out_size, void* d_ws, size_t ws_size,
                              hipStream_t stream){
  const float* s    = (const float*)d_in[0];
  const float* a    = (const float*)d_in[1];
  const float* t    = (const float*)d_in[2];
  const float* encW = (const float*)d_in[3];
  const float* encb = (const float*)d_in[4];
  const float* W1   = (const float*)d_in[5];
  const float* b1   = (const float*)d_in[6];
  const float* W2   = (const float*)d_in[7];
  const float* b2   = (const float*)d_in[8];
  const float* decW = (const float*)d_in[9];
  const float* decb = (const float*)d_in[10];
  float* out = (float*)d_out;
  float* ws  = (float*)d_ws;
  float* W2p8 = ws;                          // 65,536 floats
  float* W2c0 = ws + HID*LAT*8;              //  8,192 floats
  float* m_ws = ws + HID*LAT*9;              // 128*4096*8 floats (16.8MB)

  hipLaunchKernelGGL(repack_w2, dim3((HID*LAT*9+255)/256), dim3(256), 0, stream, W2, W2p8, W2c0);
  hipLaunchKernelGGL(spline_kernel, dim3(Bsz*8/256), dim3(256), 0, stream, a, m_ws);
  hipLaunchKernelGGL(cde_integrate, dim3(Bsz/BT), dim3(THR), 0, stream,
                     s,a,t,encW,encb,W1,b1,b2,decW,decb,W2p8,W2c0,m_ws,out);
}

// Round 6
// 8287.005 us; speedup vs baseline: 4.6800x; 1.0147x over previous
//
#include <hip/hip_runtime.h>

#define Bsz 4096
#define Lsz 128
#define NI  127
#define SD  32
#define AD  8
#define LAT 64
#define HID 128
#define BT  16
#define THR 1024

// ---------------- W2 repack ----------------
// W2 [128][64][9] -> W2p8 [j][l][8] (channels 1..8, 32B rows) + W2c0 [j][l] (channel 0)
__global__ __launch_bounds__(256) void repack_w2(const float* __restrict__ W2,
                                                 float* __restrict__ W2p8,
                                                 float* __restrict__ W2c0){
  int idx = blockIdx.x*256 + threadIdx.x;
  if (idx < HID*LAT*8){
    int x = idx & 7; int jl = idx >> 3; int l = jl & 63; int j = jl >> 6;
    W2p8[idx] = W2[(j*LAT + l)*9 + x + 1];
  } else if (idx < HID*LAT*9){
    int jl = idx - HID*LAT*8;
    W2c0[jl] = W2[(size_t)jl*9];
  }
}

// ---------------- Natural cubic spline: channels 1..8 only (t-channel is exactly linear) ----------------
// m_ws layout [i][b][8], i=0..127
__global__ __launch_bounds__(256) void spline_kernel(const float* __restrict__ a,
                                                     float* __restrict__ m_ws){
  __shared__ float cp_s[126];
  if (threadIdx.x == 0){
    float c = 0.25f; cp_s[0] = c;
    for (int i=1;i<126;i++){ c = 1.0f/(4.0f - c); cp_s[i] = c; }
  }
  __syncthreads();
  int tid = blockIdx.x*256 + threadIdx.x;   // tid = b*8 + c8, 32768 threads
  int b = tid >> 3, c8 = tid & 7;
  float dp[126];
  const float* ab = a + (size_t)b*Lsz*AD + c8;
  float x0 = ab[0];
  float x1 = ab[AD];
  for (int i=0;i<126;i++){
    float x2 = ab[(size_t)(i+2)*AD];
    float rhs = 6.0f*(x2 - 2.0f*x1 + x0);
    dp[i] = (i==0)? rhs*0.25f : (rhs - dp[i-1])*cp_s[i];
    x0 = x1; x1 = x2;
  }
  m_ws[tid] = 0.0f;                                   // m[0]
  m_ws[((size_t)127*Bsz)*8 + tid] = 0.0f;             // m[127]
  float mn = 0.0f;
  for (int k=125;k>=0;k--){
    mn = dp[k] - cp_s[k]*mn;
    m_ws[((size_t)(k+1)*Bsz)*8 + tid] = mn;
  }
}

// cross-lane helpers
#define DPP_XOR1(v) __int_as_float(__builtin_amdgcn_mov_dpp(__float_as_int(v), 0xB1, 0xF, 0xF, true))
#define DPP_XOR2(v) __int_as_float(__builtin_amdgcn_mov_dpp(__float_as_int(v), 0x4E, 0xF, 0xF, true))
#define SWZ_XOR4(v) __int_as_float(__builtin_amdgcn_ds_swizzle(__float_as_int(v), 0x101F))
#define SWZ_XOR8(v) __int_as_float(__builtin_amdgcn_ds_swizzle(__float_as_int(v), 0x201F))

// hs layout: [b][(j>>3)*12 + (j&7)], row stride 196 (measured R4: 5.9e7 conflicts, ~2-way)
#define HROW 196

// ---------------- Persistent RK4 integrator ----------------
__attribute__((amdgpu_waves_per_eu(4,4)))
__global__ __launch_bounds__(THR) void cde_integrate(
    const float* __restrict__ s, const float* __restrict__ a, const float* __restrict__ t,
    const float* __restrict__ encW, const float* __restrict__ encb,
    const float* __restrict__ W1, const float* __restrict__ b1,
    const float* __restrict__ b2, const float* __restrict__ decW, const float* __restrict__ decb,
    const float* __restrict__ W2p8, const float* __restrict__ W2c0, const float* __restrict__ m_ws,
    float* __restrict__ out)
{
  __shared__ float W1t[HID][LAT+4];    // [j][k], pad 68
  __shared__ float hs[BT][HROW];       // [b][swizzled j]
  __shared__ float zs[BT][LAT+4];      // [b][l]
  __shared__ float dXs[5][BT][8];      // dX channels 1..8 at u in {0,.25,.5,.75,1}
  __shared__ float dWs[LAT][SD];
  __shared__ float dbs[SD];

  const int tid = threadIdx.x;
  const int b0 = blockIdx.x * BT;

  // ---- weight staging ----
  for (int i=tid;i<HID*LAT;i+=THR){ int j = i & (HID-1); int k = i >> 7; W1t[j][k] = W1[k*HID+j]; }
  for (int i=tid;i<LAT*SD;i+=THR)  ((float*)dWs)[i] = decW[i];
  if (tid < SD) dbs[tid] = decb[tid];

  // ---- ownership: thread (ol = tid>>4, jg = tid&15) ----
  const int ol = tid >> 4;
  const int jg = tid & 15;

  // ---- persistent registers: W2 slice, b2 column, b1 pair ----
  float4 wa[8], wb[8]; float wc0[8];
  {
    #pragma unroll
    for (int jj=0;jj<8;jj++){
      const int j = jg*8 + jj;
      const float4* p = (const float4*)&W2p8[((size_t)j*LAT + ol)*8];
      wa[jj] = p[0]; wb[jj] = p[1];
      wc0[jj] = W2c0[j*LAT + ol];
    }
  }
  float4 b2a, b2b; float b2c0;
  {
    const float* bp = b2 + ol*9;
    b2c0 = bp[0];
    b2a.x = bp[1]; b2a.y = bp[2]; b2a.z = bp[3]; b2a.w = bp[4];
    b2b.x = bp[5]; b2b.y = bp[6]; b2b.z = bp[7]; b2b.w = bp[8];
  }
  const float b1r0 = b1[2*ol], b1r1 = b1[2*ol+1];

  // ---- encode z0 ----
  {
    const int bb = tid >> 6;
    const int li = tid & 63;
    const float* sb = s + (size_t)(b0+bb)*Lsz*SD;
    const float* ab = a + (size_t)(b0+bb)*Lsz*AD;
    const float tv = t[(size_t)(b0+bb)*Lsz];
    float acc = encb[li];
    #pragma unroll
    for (int k=0;k<SD;k++) acc = fmaf(sb[k], encW[k*LAT+li], acc);
    #pragma unroll
    for (int k=0;k<AD;k++) acc = fmaf(ab[k], encW[(SD+k)*LAT+li], acc);
    acc = fmaf(tv, encW[(SD+AD)*LAT+li], acc);
    zs[bb][li] = acc;
  }
  __syncthreads();

  // ---- decode out[:,0,:] ----
  if (tid < BT*SD){
    const int bb = tid >> 5; const int o = tid & 31;
    float acc = dbs[o];
    #pragma unroll 8
    for (int k=0;k<LAT;k++) acc = fmaf(zs[bb][k], dWs[k][o], acc);
    out[((size_t)(b0+bb)*Lsz + 0)*SD + o] = acc;
  }

  // RK4 state: thread owns z(l=ol, b=jg)
  float zb = zs[jg][ol];
  float ka = 0.f;

  for (int iv=0; iv<NI; iv++){
    // ---- dX(u) channels 1..8 at the 5 distinct u of this interval ----
    if (tid < 5*BT*8){
      int ui = tid >> 7; int r = tid & 127; int bb = r >> 3; int x8 = r & 7;
      float u = 0.25f*(float)ui;
      int gb = b0+bb;
      float m0 = m_ws[((size_t)iv    *Bsz + gb)*8 + x8];
      float m1 = m_ws[((size_t)(iv+1)*Bsz + gb)*8 + x8];
      float xd = a[((size_t)gb*Lsz + iv+1)*AD + x8] - a[((size_t)gb*Lsz + iv)*AD + x8];
      float cb = xd - (2.f*m0 + m1)*(1.f/6.f);
      float cc = 0.5f*m0;
      float cd = (m1 - m0)*(1.f/6.f);
      dXs[ui][bb][x8] = cb + (2.f*cc)*u + (3.f*cd)*(u*u);
    }

    for (int st=0; st<8; st++){
      const int ui = (st+1)>>1;      // {0,1,1,2,2,3,3,4}
      const int mode = st & 3;
      __syncthreads();               // zs, dXs readable; prev hs readers done

      // ---- GEMM1: h[jg][2ol..2ol+1] = relu(z @ W1 + b1) ----
      {
        const int j0 = 2*ol;
        float acc0 = b1r0, acc1 = b1r1;
        const float4* z4 = (const float4*)&zs[jg][0];
        const float4* w0 = (const float4*)&W1t[j0][0];
        const float4* w1 = (const float4*)&W1t[j0+1][0];
        #pragma unroll
        for (int k4=0;k4<LAT/4;k4++){
          float4 zv = z4[k4]; float4 u0 = w0[k4]; float4 u1 = w1[k4];
          acc0 = fmaf(zv.x,u0.x,acc0); acc0 = fmaf(zv.y,u0.y,acc0);
          acc0 = fmaf(zv.z,u0.z,acc0); acc0 = fmaf(zv.w,u0.w,acc0);
          acc1 = fmaf(zv.x,u1.x,acc1); acc1 = fmaf(zv.y,u1.y,acc1);
          acc1 = fmaf(zv.z,u1.z,acc1); acc1 = fmaf(zv.w,u1.w,acc1);
        }
        float2 hv; hv.x = fmaxf(acc0,0.f); hv.y = fmaxf(acc1,0.f);
        *(float2*)&hs[jg][(j0>>3)*12 + (j0&7)] = hv;
      }
      __syncthreads();               // hs ready

      // ---- pin W2 into architectural VGPRs for this stage's GEMM2 ----
      #pragma unroll
      for (int jj=0;jj<8;jj++){
        asm volatile("" : "+v"(wa[jj].x), "+v"(wa[jj].y), "+v"(wa[jj].z), "+v"(wa[jj].w),
                          "+v"(wb[jj].x), "+v"(wb[jj].y), "+v"(wb[jj].z), "+v"(wb[jj].w),
                          "+v"(wc0[jj]));
      }

      // ---- GEMM2 partials (register W2, 8-ch dX + constant t-channel) ----
      auto gemm2_batch = [&](const int bb0)->float {
        float dz[8];
        #pragma unroll
        for (int i=0;i<8;i++){
          const int b = bb0 + i;
          const float4 dxa = *(const float4*)&dXs[ui][b][0];
          const float4 dxb = *(const float4*)&dXs[ui][b][4];
          const float4 h0 = *(const float4*)&hs[b][jg*12];
          const float4 h1 = *(const float4*)&hs[b][jg*12+4];
          float acc = 0.f;
          #define STEP(JJ, HV) { \
            float wd = fmaf(wa[JJ].x,dxa.x, fmaf(wa[JJ].y,dxa.y, fmaf(wa[JJ].z,dxa.z, fmaf(wa[JJ].w,dxa.w, \
                       fmaf(wb[JJ].x,dxb.x, fmaf(wb[JJ].y,dxb.y, fmaf(wb[JJ].z,dxb.z, fmaf(wb[JJ].w,dxb.w, \
                       wc0[JJ])))))))); \
            acc = fmaf(HV, wd, acc); }
          STEP(0,h0.x) STEP(1,h0.y) STEP(2,h0.z) STEP(3,h0.w)
          STEP(4,h1.x) STEP(5,h1.y) STEP(6,h1.z) STEP(7,h1.w)
          #undef STEP
          dz[i] = acc;
        }
        // xor1 (DPP)
        const bool g1 = (jg&1);
        float nd[4];
        #pragma unroll
        for (int i=0;i<4;i++){
          float lo = dz[2*i], hi = dz[2*i+1];
          float send = g1 ? lo : hi;
          float recv = DPP_XOR1(send);
          float keep = g1 ? hi : lo;
          nd[i] = keep + recv;
        }
        // xor2 (DPP)
        const bool g2 = (jg&2);
        float md[2];
        #pragma unroll
        for (int i=0;i<2;i++){
          float lo = nd[2*i], hi = nd[2*i+1];
          float send = g2 ? lo : hi;
          float recv = DPP_XOR2(send);
          float keep = g2 ? hi : lo;
          md[i] = keep + recv;
        }
        // xor4 + xor8 (ds_swizzle)
        const bool g4 = (jg&4);
        float lo = md[0], hi = md[1];
        float send = g4 ? lo : hi;
        float recv = SWZ_XOR4(send);
        float keep = g4 ? hi : lo;
        float r = keep + recv;
        return r + SWZ_XOR8(r);
      };
      const float totA = gemm2_batch(0);
      const float totB = gemm2_batch(8);

      // ---- bias term from registers: b2[ol]·dX[jg] (+ const channel) ----
      float bias;
      {
        const float4 dja = *(const float4*)&dXs[ui][jg][0];
        const float4 djb = *(const float4*)&dXs[ui][jg][4];
        bias = fmaf(b2a.x,dja.x, fmaf(b2a.y,dja.y, fmaf(b2a.z,dja.z, fmaf(b2a.w,dja.w,
               fmaf(b2b.x,djb.x, fmaf(b2b.y,djb.y, fmaf(b2b.z,djb.z, fmaf(b2b.w,djb.w, b2c0))))))));
      }
      float dzm = ((jg&8)? totB : totA) + bias;

      // ---- RK4 bookkeeping (h = 0.5) ----
      if (mode == 0){        ka = dzm;
        zs[jg][ol] = zb + 0.25f*dzm;
      } else if (mode == 1){ ka = fmaf(2.f, dzm, ka);
        zs[jg][ol] = zb + 0.25f*dzm;
      } else if (mode == 2){ ka = fmaf(2.f, dzm, ka);
        zs[jg][ol] = zb + 0.5f*dzm;
      } else {               ka += dzm;
        zb = fmaf(0.5f/6.f, ka, zb);
        zs[jg][ol] = zb;
      }
    }

    __syncthreads();   // final z in zs
    // ---- decode out[:, iv+1, :] ----
    if (tid < BT*SD){
      const int bb = tid >> 5; const int o = tid & 31;
      float acc = dbs[o];
      #pragma unroll 8
      for (int k=0;k<LAT;k++) acc = fmaf(zs[bb][k], dWs[k][o], acc);
      out[((size_t)(b0+bb)*Lsz + (iv+1))*SD + o] = acc;
    }
  }
}

extern "C" void kernel_launch(void* const* d_in, const int* in_sizes, int n_in,
                              void* d_out, int out_size, void* d_ws, size_t ws_size,
                              hipStream_t stream){
  const float* s    = (const float*)d_in[0];
  const float* a    = (const float*)d_in[1];
  const float* t    = (const float*)d_in[2];
  const float* encW = (const float*)d_in[3];
  const float* encb = (const float*)d_in[4];
  const float* W1   = (const float*)d_in[5];
  const float* b1   = (const float*)d_in[6];
  const float* W2   = (const float*)d_in[7];
  const float* b2   = (const float*)d_in[8];
  const float* decW = (const float*)d_in[9];
  const float* decb = (const float*)d_in[10];
  float* out = (float*)d_out;
  float* ws  = (float*)d_ws;
  float* W2p8 = ws;                          // 65,536 floats
  float* W2c0 = ws + HID*LAT*8;              //  8,192 floats
  float* m_ws = ws + HID*LAT*9;              // 128*4096*8 floats (16.8MB)

  hipLaunchKernelGGL(repack_w2, dim3((HID*LAT*9+255)/256), dim3(256), 0, stream, W2, W2p8, W2c0);
  hipLaunchKernelGGL(spline_kernel, dim3(Bsz*8/256), dim3(256), 0, stream, a, m_ws);
  hipLaunchKernelGGL(cde_integrate, dim3(Bsz/BT), dim3(THR), 0, stream,
                     s,a,t,encW,encb,W1,b1,b2,decW,decb,W2p8,W2c0,m_ws,out);
}